// Round 3
// baseline (114.826 us; speedup 1.0000x reference)
//
#include <hip/hip_runtime.h>

#define SIDE 128
#define PI_F 3.14159265358979f

// One block per batch image. The whole 128x128 fp32 image lives in LDS
// (65536 B = the per-workgroup max). No global atomics, no zero kernel:
// plain coalesced float4 stores overwrite the poisoned d_out at the end.
//
// Gaussians are ultra-narrow: c = pi*4*pi/ff_b >= 2*pi^2 (ff_b <= 2.0), so
// the kept window (terms > ~1e-14 abs; threshold is 3.48) spans <= 3x3 px.
// Separable: exp(-c*(dx^2+dy^2)) = wx[j]*wy[i] -> <=6 exps + <=9 LDS adds.
__global__ void __launch_bounds__(1024) potential_lds(
        const float* __restrict__ coords,
        const float* __restrict__ ff_a,
        const float* __restrict__ ff_b,
        float* __restrict__ out,
        int A) {
    __shared__ float img[SIDE * SIDE];   // 64 KiB
    const int b = blockIdx.x;
    const int t = threadIdx.x;           // 0..1023

    // zero the LDS image: 16 floats per thread
    #pragma unroll
    for (int k = 0; k < (SIDE * SIDE) / 1024; ++k)
        img[t + k * 1024] = 0.0f;
    __syncthreads();

    const float* cb = coords + (size_t)b * A * 3;
    const int pairs = A * 5;             // 10240

    // lane->pair mapping: a = p % A  => consecutive lanes hit consecutive
    // atoms (coalesced coord loads, and no two lanes of a wave share an
    // atom => no intra-wave same-address LDS-atomic serialization).
    for (int p = t; p < pairs; p += 1024) {
        int a = p % A;
        int f = p / A;

        float x  = cb[a * 3 + 0];
        float y  = cb[a * 3 + 1];
        float fa = ff_a[a * 5 + f];
        float fb = ff_b[a * 5 + f];

        float invb = (4.0f * PI_F) / fb;
        float coef = fa * invb;          // peak amplitude in [~3.1, ~50.3]
        float c    = PI_F * invb;        // exponent scale in [~19.7, ~79]

        float cx = x + 64.0f;            // column center (j axis)
        float cy = y + 64.0f;            // row center (i axis)

        // keep pixels where coef*exp(-c*d2) > ~1e-14  <=>  c*d2 < ln(coef)+32
        float r = sqrtf((__logf(coef) + 32.0f) / c);   // <= 1.35 px

        int j0 = max(0, (int)ceilf(cx - r));
        int j1 = min(SIDE - 1, (int)floorf(cx + r));
        int i0 = max(0, (int)ceilf(cy - r));
        int i1 = min(SIDE - 1, (int)floorf(cy + r));
        if (j1 < j0 || i1 < i0) continue;   // blob entirely off-grid

        // separable weights (<=3 each)
        float wx[3], wy[3];
        for (int j = j0; j <= j1; ++j) {
            float dx = (float)j - cx;
            wx[j - j0] = __expf(-c * dx * dx);
        }
        for (int i = i0; i <= i1; ++i) {
            float dy = (float)i - cy;
            wy[i - i0] = coef * __expf(-c * dy * dy);
        }
        for (int i = i0; i <= i1; ++i) {
            float wyi = wy[i - i0];
            float* row = img + i * SIDE;
            for (int j = j0; j <= j1; ++j)
                atomicAdd(&row[j], wyi * wx[j - j0]);   // ds_add_f32
        }
    }
    __syncthreads();

    // flush LDS image -> global, coalesced float4 (overwrites 0xAA poison)
    float4* outb = (float4*)(out + (size_t)b * (SIDE * SIDE));
    const float4* imgv = (const float4*)img;
    #pragma unroll
    for (int k = 0; k < (SIDE * SIDE) / 4 / 1024; ++k)   // 4 float4 per thread
        outb[t + k * 1024] = imgv[t + k * 1024];
}

extern "C" void kernel_launch(void* const* d_in, const int* in_sizes, int n_in,
                              void* d_out, int out_size, void* d_ws, size_t ws_size,
                              hipStream_t stream) {
    const float* coords = (const float*)d_in[0];
    const float* ffa    = (const float*)d_in[1];
    const float* ffb    = (const float*)d_in[2];
    float* out = (float*)d_out;

    int A = in_sizes[1] / 5;          // 2048
    int B = in_sizes[0] / (A * 3);    // 4

    potential_lds<<<B, 1024, 0, stream>>>(coords, ffa, ffb, out, A);
}

// Round 4
// 66.992 us; speedup vs baseline: 1.7140x; 1.7140x over previous
//
#include <hip/hip_runtime.h>

#define SIDE 128
#define PI_F 3.14159265358979f
// Max window half-width: r = sqrt((ln(coef)+32)/c), coef<=2*4pi/0.5=50.27,
// c = pi*4pi/ff_b >= 2*pi^2 = 19.74  =>  r <= 1.35. Use 1.4 for safety.
#define RMAX 1.4f

// One block per (batch, 2-row stripe): grid (64,4) = 256 blocks = 1/CU.
// Phase 1: filter+compact atoms whose blob can touch the stripe (LDS list).
// Phase 2: full-lane processing of the list into a 2x128 LDS stripe (ds_add).
// Phase 3: plain coalesced float4 store of the disjoint stripe (no zero pass,
// no global atomics).
__global__ void __launch_bounds__(256) potential_stripe(
        const float* __restrict__ coords,
        const float* __restrict__ ff_a,
        const float* __restrict__ ff_b,
        float* __restrict__ out,
        int A) {
    const int s    = blockIdx.x;        // stripe index, rows [2s, 2s+1]
    const int b    = blockIdx.y;
    const int row0 = s * 2;
    const int t    = threadIdx.x;       // 0..255

    __shared__ float img[2 * SIDE];     // 1 KB stripe accumulator
    __shared__ int   cnt;
    __shared__ int   list[2048];        // surviving atom indices

    img[t] = 0.0f;                      // 256 floats, one per thread
    if (t == 0) cnt = 0;
    __syncthreads();

    const float* cb = coords + (size_t)b * A * 3;

    // ---- Phase 1: filter atoms by row window (all 5 f share the center) ----
    const float ylo = (float)row0 - RMAX;
    const float yhi = (float)(row0 + 1) + RMAX;
    for (int a = t; a < A; a += 256) {  // 8 tests/thread
        float x  = cb[a * 3 + 0];
        float y  = cb[a * 3 + 1];
        float cx = x + 64.0f;
        float cy = y + 64.0f;
        if (cy >= ylo && cy <= yhi && cx >= -RMAX && cx <= 127.0f + RMAX) {
            list[atomicAdd(&cnt, 1)] = a;
        }
    }
    __syncthreads();

    // ---- Phase 2: scatter surviving blobs into the LDS stripe ----
    const int n = cnt;                  // busiest stripe ~300
    for (int k = t; k < n; k += 256) {
        int a = list[k];
        float cx = cb[a * 3 + 0] + 64.0f;
        float cy = cb[a * 3 + 1] + 64.0f;
        #pragma unroll
        for (int f = 0; f < 5; ++f) {
            float fa = ff_a[a * 5 + f];
            float fb = ff_b[a * 5 + f];
            float invb = (4.0f * PI_F) / fb;
            float coef = fa * invb;     // peak amplitude
            float c    = PI_F * invb;   // exponent scale
            // keep terms > ~1e-14 abs (threshold is 3.48)
            float r = sqrtf((__logf(coef) + 32.0f) / c);

            int i0 = max(row0,     (int)ceilf(cy - r));
            int i1 = min(row0 + 1, (int)floorf(cy + r));
            int j0 = max(0,        (int)ceilf(cx - r));
            int j1 = min(SIDE - 1, (int)floorf(cx + r));

            for (int i = i0; i <= i1; ++i) {        // <= 2 rows
                float dy  = (float)i - cy;
                float wyi = coef * __expf(-c * dy * dy);
                float* rowp = img + (i - row0) * SIDE;
                for (int j = j0; j <= j1; ++j) {    // <= 3 cols
                    float dx = (float)j - cx;
                    atomicAdd(&rowp[j], wyi * __expf(-c * dx * dx)); // ds_add
                }
            }
        }
    }
    __syncthreads();

    // ---- Phase 3: store the disjoint stripe (overwrites 0xAA poison) ----
    float4* ov = (float4*)(out + ((size_t)b * SIDE + row0) * SIDE);
    if (t < (2 * SIDE) / 4)             // 64 float4 = 256 floats
        ov[t] = ((const float4*)img)[t];
}

extern "C" void kernel_launch(void* const* d_in, const int* in_sizes, int n_in,
                              void* d_out, int out_size, void* d_ws, size_t ws_size,
                              hipStream_t stream) {
    const float* coords = (const float*)d_in[0];
    const float* ffa    = (const float*)d_in[1];
    const float* ffb    = (const float*)d_in[2];
    float* out = (float*)d_out;

    int A = in_sizes[1] / 5;            // 2048
    int B = in_sizes[0] / (A * 3);      // 4

    dim3 grid(SIDE / 2, B);             // (64 stripes, 4 batches) = 256 blocks
    potential_stripe<<<grid, 256, 0, stream>>>(coords, ffa, ffb, out, A);
}

// Round 5
// 63.939 us; speedup vs baseline: 1.7959x; 1.0477x over previous
//
#include <hip/hip_runtime.h>

#define SIDE 128
#define PI_F 3.14159265358979f
// Max window half-width: r = sqrt((ln(coef)+32)/c), coef<=2*4pi/0.5=50.27,
// c = pi*4pi/ff_b >= 2*pi^2 = 19.74  =>  r <= 1.35. Use 1.4 for safety.
#define RMAX 1.4f
#define BLK 512

// One block per (batch, 2-row stripe): grid (64,4) = 256 blocks, 512 thr
// (8 waves/CU). Phase 1: ballot-compacted atom filter (1 same-address LDS
// atomic per wave per round, vs 2048/block in R4) storing cx,cy,idx in LDS.
// Phase 2: full-lane scatter of <=3x3 separable Gaussian windows into a
// 2x128 LDS stripe via ds_add. Phase 3: coalesced float4 store of the
// disjoint stripe (overwrites 0xAA poison; no zero kernel, no global atomics).
__global__ void __launch_bounds__(BLK) potential_stripe(
        const float* __restrict__ coords,
        const float* __restrict__ ff_a,
        const float* __restrict__ ff_b,
        float* __restrict__ out,
        int A) {
    const int s    = blockIdx.x;        // stripe index, rows [2s, 2s+1]
    const int b    = blockIdx.y;
    const int row0 = s * 2;
    const int t    = threadIdx.x;       // 0..511
    const int lane = t & 63;

    __shared__ float img[2 * SIDE];     // 1 KB stripe accumulator
    __shared__ int   cnt;
    __shared__ float lx[2048], ly[2048];
    __shared__ int   li[2048];          // compacted centers + atom index

    if (t < 2 * SIDE) img[t] = 0.0f;
    if (t == 0) cnt = 0;
    __syncthreads();

    const float* cb = coords + (size_t)b * A * 3;

    // ---- Phase 1: filter atoms by row window (all 5 f share the center) ----
    const float ylo = (float)row0 - RMAX;
    const float yhi = (float)(row0 + 1) + RMAX;
    for (int a0 = 0; a0 < A; a0 += BLK) {        // 4 rounds
        int a = a0 + t;
        float cx = 0.f, cy = 0.f;
        bool keep = false;
        if (a < A) {
            cx = cb[a * 3 + 0] + 64.0f;
            cy = cb[a * 3 + 1] + 64.0f;
            keep = (cy >= ylo) & (cy <= yhi) &
                   (cx >= -RMAX) & (cx <= 127.0f + RMAX);
        }
        unsigned long long m = __ballot(keep);
        int nw  = __popcll(m);
        int pos = __popcll(m & ((1ull << lane) - 1ull));
        int base = 0;
        if (lane == 0 && nw) base = atomicAdd(&cnt, nw);
        base = __shfl(base, 0);
        if (keep) {
            int k = base + pos;
            lx[k] = cx; ly[k] = cy; li[k] = a;
        }
    }
    __syncthreads();

    // ---- Phase 2: scatter surviving blobs into the LDS stripe ----
    const int n = cnt;                  // busiest stripe ~300
    for (int k = t; k < n; k += BLK) {
        float cx = lx[k];
        float cy = ly[k];
        int   a  = li[k];
        #pragma unroll
        for (int f = 0; f < 5; ++f) {
            float fa = ff_a[a * 5 + f];
            float fb = ff_b[a * 5 + f];
            float invb = (4.0f * PI_F) / fb;
            float coef = fa * invb;     // peak amplitude
            float c    = PI_F * invb;   // exponent scale
            // keep terms > ~1e-14 abs (pass threshold is 3.48)
            float r = sqrtf((__logf(coef) + 32.0f) / c);

            int i0 = max(row0,     (int)ceilf(cy - r));
            int i1 = min(row0 + 1, (int)floorf(cy + r));
            int j0 = max(0,        (int)ceilf(cx - r));
            int j1 = min(SIDE - 1, (int)floorf(cx + r));

            for (int i = i0; i <= i1; ++i) {        // <= 2 rows
                float dy  = (float)i - cy;
                float wyi = coef * __expf(-c * dy * dy);
                float* rowp = img + (i - row0) * SIDE;
                for (int j = j0; j <= j1; ++j) {    // <= 3 cols
                    float dx = (float)j - cx;
                    atomicAdd(&rowp[j], wyi * __expf(-c * dx * dx)); // ds_add
                }
            }
        }
    }
    __syncthreads();

    // ---- Phase 3: store the disjoint stripe (overwrites 0xAA poison) ----
    if (t < (2 * SIDE) / 4) {           // 64 float4 = 256 floats
        float4* ov = (float4*)(out + ((size_t)b * SIDE + row0) * SIDE);
        ov[t] = ((const float4*)img)[t];
    }
}

extern "C" void kernel_launch(void* const* d_in, const int* in_sizes, int n_in,
                              void* d_out, int out_size, void* d_ws, size_t ws_size,
                              hipStream_t stream) {
    const float* coords = (const float*)d_in[0];
    const float* ffa    = (const float*)d_in[1];
    const float* ffb    = (const float*)d_in[2];
    float* out = (float*)d_out;

    int A = in_sizes[1] / 5;            // 2048
    int B = in_sizes[0] / (A * 3);      // 4

    dim3 grid(SIDE / 2, B);             // (64 stripes, 4 batches) = 256 blocks
    potential_stripe<<<grid, BLK, 0, stream>>>(coords, ffa, ffb, out, A);
}